// Round 4
// baseline (10000.372 us; speedup 1.0000x reference)
//
#include <hip/hip_runtime.h>
#include <hip/hip_bf16.h>

#define B_ 64
#define T_ 512
#define D_ 512
#define H_ 1024
#define LN_EPS 1e-3f
#define UPAD 1032

typedef short bf16x8 __attribute__((ext_vector_type(8)));
typedef float f32x4  __attribute__((ext_vector_type(4)));
typedef unsigned int u32x4 __attribute__((ext_vector_type(4)));

static __device__ __forceinline__ float tf(float x) {
    // tanh(x) = 1 - 2/(e^{2x}+1), exact formula, ~1e-7 abs error
    float e = __expf(2.0f * x);
    return 1.0f - 2.0f / (e + 1.0f);
}
static __device__ __forceinline__ unsigned fu(float x) { return __float_as_uint(x); }
static __device__ __forceinline__ float uf(unsigned x) { return __uint_as_float(x); }

// ---------------------------------------------------------------------------
// GEMM1 (fp32 anchor): out = X@W + b   M=32768 K=512 N=1024  (~0.34 ms)
// ---------------------------------------------------------------------------
__global__ __launch_bounds__(256) void gemm1_kernel(
    const float* __restrict__ X, const float* __restrict__ W,
    const float* __restrict__ bias, float* __restrict__ out)
{
    __shared__ float sA[16][64];
    __shared__ float sB[16][64];
    const int m0 = blockIdx.x * 64;
    const int n0 = blockIdx.y * 64;
    const int t  = threadIdx.x;
    const int tx = t & 15, ty = t >> 4;
    const int ar = t >> 2, ak = (t & 3) * 4;
    const int bk = t >> 4, bc = (t & 15) * 4;

    float acc[4][4] = {};
    for (int k0 = 0; k0 < D_; k0 += 16) {
        float4 av = *(const float4*)(X + (size_t)(m0 + ar) * D_ + k0 + ak);
        float4 bv = *(const float4*)(W + (size_t)(k0 + bk) * H_ + n0 + bc);
        __syncthreads();
        sA[ak + 0][ar] = av.x; sA[ak + 1][ar] = av.y;
        sA[ak + 2][ar] = av.z; sA[ak + 3][ar] = av.w;
        *(float4*)&sB[bk][bc] = bv;
        __syncthreads();
#pragma unroll
        for (int kk = 0; kk < 16; ++kk) {
            float4 a = *(const float4*)&sA[kk][ty * 4];
            float4 b = *(const float4*)&sB[kk][tx * 4];
            acc[0][0] += a.x*b.x; acc[0][1] += a.x*b.y; acc[0][2] += a.x*b.z; acc[0][3] += a.x*b.w;
            acc[1][0] += a.y*b.x; acc[1][1] += a.y*b.y; acc[1][2] += a.y*b.z; acc[1][3] += a.y*b.w;
            acc[2][0] += a.z*b.x; acc[2][1] += a.z*b.y; acc[2][2] += a.z*b.z; acc[2][3] += a.z*b.w;
            acc[3][0] += a.w*b.x; acc[3][1] += a.w*b.y; acc[3][2] += a.w*b.z; acc[3][3] += a.w*b.w;
        }
    }
#pragma unroll
    for (int i = 0; i < 4; ++i) {
        const int row = m0 + ty * 4 + i;
        const int col = n0 + tx * 4;
        float4 bv = *(const float4*)(bias + col);
        float4 o;
        o.x = acc[i][0] + bv.x; o.y = acc[i][1] + bv.y;
        o.z = acc[i][2] + bv.z; o.w = acc[i][3] + bv.w;
        *(float4*)(out + (size_t)row * H_ + col) = o;
    }
}

// ---------------------------------------------------------------------------
// Persistent recurrence, barrier-free tag-carried dataflow.
// 128 WGs = 4 rowgroups(16 rows) x 32 colgroups(32 cols).
// Publishes raw z (f32, 2-bit step tag in low mantissa bits) + stats partials
// (8B, tag in Q low bits). Consumers rebuild h = tanh(LN(z)) locally.
// z and stats double-buffered by step parity; tags mod 4; skew <= 1 step.
// ---------------------------------------------------------------------------
__global__ __launch_bounds__(256, 1) void rnn_kernel(
    const float* __restrict__ U, const float* __restrict__ gamma,
    const float* __restrict__ beta, float* __restrict__ out,
    unsigned int* __restrict__ zg, unsigned long long* __restrict__ sg)
{
    extern __shared__ char smem[];
    unsigned short* Uhi = (unsigned short*)smem;            // [32][UPAD]
    unsigned short* Ulo = Uhi + 32 * UPAD;                  // [32][UPAD]
    float* gls = (float*)(Ulo + 32 * UPAD);                 // [1024]
    float* bls = gls + 1024;                                // [1024]
    float* red = bls + 1024;                                // [2][64][4]
    float* smu = red + 512;                                 // [16]
    float* srs = smu + 16;                                  // [16]

    const int wg  = blockIdx.x;
    const int rg  = wg >> 5;
    const int cg  = wg & 31;
    const int tid = threadIdx.x;
    const int w   = tid >> 6;
    const int l   = tid & 63;
    const int ct  = w >> 1;
    const int kh  = w & 1;
    const int lc  = l & 15;
    const int lh  = l >> 4;
    const int khk = kh * 512;
    const int lhk = lh * 8;

    // ---- stage U[:, cg*32..+32] into LDS as bf16 hi/lo, [col][k]
    const int c0 = cg * 32;
    for (int kk = 0; kk < H_; kk += 32) {
        int k  = kk + (tid >> 3);
        int c4 = (tid & 7) * 4;
        float4 u = *(const float4*)(U + (size_t)k * H_ + c0 + c4);
        float uu[4] = {u.x, u.y, u.z, u.w};
#pragma unroll
        for (int e = 0; e < 4; ++e) {
            unsigned hb = fu(uu[e]) >> 16;                       // truncate hi
            float    lf = uu[e] - uf((fu(uu[e]) & 0xFFFF0000u));
            unsigned lb = fu(lf) >> 16;
            Uhi[(size_t)(c4 + e) * UPAD + k] = (unsigned short)hb;
            Ulo[(size_t)(c4 + e) * UPAD + k] = (unsigned short)lb;
        }
    }
    // gamma/beta to LDS
    {
        int i = tid * 4;
        *(float4*)&gls[i] = *(const float4*)(gamma + i);
        *(float4*)&bls[i] = *(const float4*)(beta + i);
    }
    __syncthreads();

    const int col = c0 + ct * 16 + lc;
    const float gmv = gls[col];
    const float btv = bls[col];

    const unsigned short* ubh = Uhi + (size_t)(ct * 16 + lc) * UPAD + khk;
    const unsigned short* ubl = Ulo + (size_t)(ct * 16 + lc) * UPAD + khk;

    const size_t zlane_off = ((size_t)(rg * 16 + lc) * 1024 + khk + lhk) * 4;
    const size_t srow_off  = ((size_t)(rg * 16 + (tid >> 4)) * 64 + (tid & 15) * 4) * 8;

    float zz[4] = {0.f, 0.f, 0.f, 0.f};

#define TAGBAD(A,B) (__any((int)(((((A).x^tg)|((A).y^tg)|((A).z^tg)|((A).w^tg)| \
                     ((B).x^tg)|((B).y^tg)|((B).z^tg)|((B).w^tg)) & 3u) != 0u)))

#pragma unroll 1
    for (int t = 0; t < T_; ++t) {
        float xwv[4];
        if (t > 0) {
            const unsigned tg = (unsigned)(t & 3);
            const char* zladdr = (const char*)zg + (size_t)((t & 1) ^ 1) * 262144 + zlane_off;
            const char* sladdr = (const char*)sg + (size_t)((t & 1) ^ 1) * 32768 + srow_off;

            u32x4 za0,zb0,za1,zb1,za2,zb2,za3,zb3,za4,zb4,za5,zb5,za6,zb6,za7,zb7,
                  za8,zb8,za9,zb9,za10,zb10,za11,zb11,za12,zb12,za13,zb13,za14,zb14,za15,zb15,
                  q0,q1;
            asm volatile(
                "global_load_dwordx4 %0, %[za], off sc0 sc1\n\t"
                "global_load_dwordx4 %1, %[za], off offset:16 sc0 sc1\n\t"
                "global_load_dwordx4 %2, %[za], off offset:128 sc0 sc1\n\t"
                "global_load_dwordx4 %3, %[za], off offset:144 sc0 sc1\n\t"
                "global_load_dwordx4 %4, %[za], off offset:256 sc0 sc1\n\t"
                "global_load_dwordx4 %5, %[za], off offset:272 sc0 sc1\n\t"
                "global_load_dwordx4 %6, %[za], off offset:384 sc0 sc1\n\t"
                "global_load_dwordx4 %7, %[za], off offset:400 sc0 sc1\n\t"
                "global_load_dwordx4 %8, %[za], off offset:512 sc0 sc1\n\t"
                "global_load_dwordx4 %9, %[za], off offset:528 sc0 sc1\n\t"
                "global_load_dwordx4 %10, %[za], off offset:640 sc0 sc1\n\t"
                "global_load_dwordx4 %11, %[za], off offset:656 sc0 sc1\n\t"
                "global_load_dwordx4 %12, %[za], off offset:768 sc0 sc1\n\t"
                "global_load_dwordx4 %13, %[za], off offset:784 sc0 sc1\n\t"
                "global_load_dwordx4 %14, %[za], off offset:896 sc0 sc1\n\t"
                "global_load_dwordx4 %15, %[za], off offset:912 sc0 sc1\n\t"
                "global_load_dwordx4 %16, %[za], off offset:1024 sc0 sc1\n\t"
                "global_load_dwordx4 %17, %[za], off offset:1040 sc0 sc1\n\t"
                "global_load_dwordx4 %18, %[za], off offset:1152 sc0 sc1\n\t"
                "global_load_dwordx4 %19, %[za], off offset:1168 sc0 sc1\n\t"
                "global_load_dwordx4 %20, %[za], off offset:1280 sc0 sc1\n\t"
                "global_load_dwordx4 %21, %[za], off offset:1296 sc0 sc1\n\t"
                "global_load_dwordx4 %22, %[za], off offset:1408 sc0 sc1\n\t"
                "global_load_dwordx4 %23, %[za], off offset:1424 sc0 sc1\n\t"
                "global_load_dwordx4 %24, %[za], off offset:1536 sc0 sc1\n\t"
                "global_load_dwordx4 %25, %[za], off offset:1552 sc0 sc1\n\t"
                "global_load_dwordx4 %26, %[za], off offset:1664 sc0 sc1\n\t"
                "global_load_dwordx4 %27, %[za], off offset:1680 sc0 sc1\n\t"
                "global_load_dwordx4 %28, %[za], off offset:1792 sc0 sc1\n\t"
                "global_load_dwordx4 %29, %[za], off offset:1808 sc0 sc1\n\t"
                "global_load_dwordx4 %30, %[za], off offset:1920 sc0 sc1\n\t"
                "global_load_dwordx4 %31, %[za], off offset:1936 sc0 sc1\n\t"
                "global_load_dwordx4 %32, %[sa], off sc0 sc1\n\t"
                "global_load_dwordx4 %33, %[sa], off offset:16 sc0 sc1\n\t"
                "s_waitcnt vmcnt(0)"
                : "=&v"(za0),"=&v"(zb0),"=&v"(za1),"=&v"(zb1),"=&v"(za2),"=&v"(zb2),
                  "=&v"(za3),"=&v"(zb3),"=&v"(za4),"=&v"(zb4),"=&v"(za5),"=&v"(zb5),
                  "=&v"(za6),"=&v"(zb6),"=&v"(za7),"=&v"(zb7),"=&v"(za8),"=&v"(zb8),
                  "=&v"(za9),"=&v"(zb9),"=&v"(za10),"=&v"(zb10),"=&v"(za11),"=&v"(zb11),
                  "=&v"(za12),"=&v"(zb12),"=&v"(za13),"=&v"(zb13),"=&v"(za14),"=&v"(zb14),
                  "=&v"(za15),"=&v"(zb15),"=&v"(q0),"=&v"(q1)
                : [za]"v"(zladdr), [sa]"v"(sladdr)
                : "memory");

            // ---- stats: check tags, retry (rare), reduce
            while ((((q0.y ^ tg) | (q0.w ^ tg) | (q1.y ^ tg) | (q1.w ^ tg)) & 3u) != 0u) {
                asm volatile(
                    "global_load_dwordx4 %0, %2, off sc0 sc1\n\t"
                    "global_load_dwordx4 %1, %2, off offset:16 sc0 sc1\n\t"
                    "s_waitcnt vmcnt(0)"
                    : "=&v"(q0), "=&v"(q1) : "v"(sladdr) : "memory");
            }
            {
                float S = uf(q0.x) + uf(q0.z) + uf(q1.x) + uf(q1.z);
                float Q = uf(q0.y) + uf(q0.w) + uf(q1.y) + uf(q1.w);
#pragma unroll
                for (int m = 1; m < 16; m <<= 1) {
                    S += __shfl_xor(S, m);
                    Q += __shfl_xor(Q, m);
                }
                float mu  = S * (1.0f / H_);
                float var = Q * (1.0f / H_) - mu * mu;
                if ((tid & 15) == 0) {
                    smu[tid >> 4] = mu;
                    srs[tid >> 4] = rsqrtf(var + LN_EPS);
                }
            }
            __syncthreads();

            // ---- finalize PREVIOUS step's own tile -> out[b, t-1, col]
            if (kh == 0) {
#pragma unroll
                for (int j = 0; j < 4; ++j) {
                    int r = lh * 4 + j;
                    int b = rg * 16 + r;
                    float o = tf((zz[j] - smu[r]) * srs[r] * gmv + btv);
                    out[((size_t)b * T_ + (t - 1)) * H_ + col] = o;
                }
                // prefetch this step's xW
#pragma unroll
                for (int j = 0; j < 4; ++j)
                    xwv[j] = out[((size_t)(rg * 16 + lh * 4 + j) * T_ + t) * H_ + col];
            }

            // ---- z tags: check all 16 slices, retry stale ones
            unsigned zmask = 0;
#define ZCHK(s) if (TAGBAD(za##s, zb##s)) zmask |= (1u << (s));
            ZCHK(0) ZCHK(1) ZCHK(2) ZCHK(3) ZCHK(4) ZCHK(5) ZCHK(6) ZCHK(7)
            ZCHK(8) ZCHK(9) ZCHK(10) ZCHK(11) ZCHK(12) ZCHK(13) ZCHK(14) ZCHK(15)
#define ZRETRY(s) if (zmask & (1u << (s))) { \
                asm volatile("global_load_dwordx4 %0, %2, off sc0 sc1\n\t" \
                             "global_load_dwordx4 %1, %2, off offset:16 sc0 sc1\n\t" \
                             "s_waitcnt vmcnt(0)" \
                             : "=&v"(za##s), "=&v"(zb##s) \
                             : "v"((const void*)(zladdr + (s) * 128)) : "memory"); \
                if (!TAGBAD(za##s, zb##s)) zmask &= ~(1u << (s)); }
            while (zmask) {
                ZRETRY(0) ZRETRY(1) ZRETRY(2) ZRETRY(3) ZRETRY(4) ZRETRY(5)
                ZRETRY(6) ZRETRY(7) ZRETRY(8) ZRETRY(9) ZRETRY(10) ZRETRY(11)
                ZRETRY(12) ZRETRY(13) ZRETRY(14) ZRETRY(15)
            }

            // ---- rebuild h = tanh(LN(z)) per slice, MFMA vs U (LDS)
            const float mul = smu[lc];
            const float rsl = srs[lc];
            f32x4 acc[4] = {{0.f,0.f,0.f,0.f},{0.f,0.f,0.f,0.f},
                            {0.f,0.f,0.f,0.f},{0.f,0.f,0.f,0.f}};
#define ZCOMP(s) { \
                const int kk = khk + (s) * 32 + lhk; \
                float4 g0 = *(const float4*)&gls[kk]; \
                float4 g1 = *(const float4*)&gls[kk + 4]; \
                float4 e0 = *(const float4*)&bls[kk]; \
                float4 e1 = *(const float4*)&bls[kk + 4]; \
                float h0 = tf((uf(za##s.x) - mul) * rsl * g0.x + e0.x); \
                float h1 = tf((uf(za##s.y) - mul) * rsl * g0.y + e0.y); \
                float h2 = tf((uf(za##s.z) - mul) * rsl * g0.z + e0.z); \
                float h3 = tf((uf(za##s.w) - mul) * rsl * g0.w + e0.w); \
                float h4 = tf((uf(zb##s.x) - mul) * rsl * g1.x + e1.x); \
                float h5 = tf((uf(zb##s.y) - mul) * rsl * g1.y + e1.y); \
                float h6 = tf((uf(zb##s.z) - mul) * rsl * g1.z + e1.z); \
                float h7 = tf((uf(zb##s.w) - mul) * rsl * g1.w + e1.w); \
                float o0 = h0 - uf(fu(h0) & 0xFFFF0000u); \
                float o1 = h1 - uf(fu(h1) & 0xFFFF0000u); \
                float o2 = h2 - uf(fu(h2) & 0xFFFF0000u); \
                float o3 = h3 - uf(fu(h3) & 0xFFFF0000u); \
                float o4 = h4 - uf(fu(h4) & 0xFFFF0000u); \
                float o5 = h5 - uf(fu(h5) & 0xFFFF0000u); \
                float o6 = h6 - uf(fu(h6) & 0xFFFF0000u); \
                float o7 = h7 - uf(fu(h7) & 0xFFFF0000u); \
                union { bf16x8 v; unsigned u[4]; } ah, al; \
                ah.u[0] = __builtin_amdgcn_perm(fu(h1), fu(h0), 0x07060302u); \
                ah.u[1] = __builtin_amdgcn_perm(fu(h3), fu(h2), 0x07060302u); \
                ah.u[2] = __builtin_amdgcn_perm(fu(h5), fu(h4), 0x07060302u); \
                ah.u[3] = __builtin_amdgcn_perm(fu(h7), fu(h6), 0x07060302u); \
                al.u[0] = __builtin_amdgcn_perm(fu(o1), fu(o0), 0x07060302u); \
                al.u[1] = __builtin_amdgcn_perm(fu(o3), fu(o2), 0x07060302u); \
                al.u[2] = __builtin_amdgcn_perm(fu(o5), fu(o4), 0x07060302u); \
                al.u[3] = __builtin_amdgcn_perm(fu(o7), fu(o6), 0x07060302u); \
                bf16x8 bh = *(const bf16x8*)(ubh + (s) * 32 + lhk); \
                bf16x8 bl = *(const bf16x8*)(ubl + (s) * 32 + lhk); \
                acc[(s) & 3] = __builtin_amdgcn_mfma_f32_16x16x32_bf16(ah.v, bh, acc[(s) & 3], 0, 0, 0); \
                acc[(s) & 3] = __builtin_amdgcn_mfma_f32_16x16x32_bf16(ah.v, bl, acc[(s) & 3], 0, 0, 0); \
                acc[(s) & 3] = __builtin_amdgcn_mfma_f32_16x16x32_bf16(al.v, bh, acc[(s) & 3], 0, 0, 0); \
            }
            ZCOMP(0) ZCOMP(1) ZCOMP(2) ZCOMP(3) ZCOMP(4) ZCOMP(5) ZCOMP(6) ZCOMP(7)
            ZCOMP(8) ZCOMP(9) ZCOMP(10) ZCOMP(11) ZCOMP(12) ZCOMP(13) ZCOMP(14) ZCOMP(15)

            f32x4 z4 = (acc[0] + acc[1]) + (acc[2] + acc[3]);
            if (kh == 1) *(f32x4*)(red + (size_t)(ct * 64 + l) * 4) = z4;
            __syncthreads();
            if (kh == 0) {
                z4 += *(const f32x4*)(red + (size_t)(ct * 64 + l) * 4);
#pragma unroll
                for (int j = 0; j < 4; ++j) zz[j] = z4[j] + xwv[j];
            }
        } else {
            // t == 0: z = xW only
            if (kh == 0) {
#pragma unroll
                for (int j = 0; j < 4; ++j)
                    zz[j] = out[((size_t)(rg * 16 + lh * 4 + j) * T_ + 0) * H_ + col];
            }
        }

        // ---- publish z^t (tagged) + stats partial (tagged)
        const unsigned tgp = (unsigned)((t + 1) & 3);
        const int pt = t & 1;
        if (kh == 0) {
            float s_[4], q_[4];
#pragma unroll
            for (int j = 0; j < 4; ++j) { s_[j] = zz[j]; q_[j] = zz[j] * zz[j]; }
#pragma unroll
            for (int m = 1; m < 16; m <<= 1) {
#pragma unroll
                for (int j = 0; j < 4; ++j) {
                    s_[j] += __shfl_xor(s_[j], m);
                    q_[j] += __shfl_xor(q_[j], m);
                }
            }
            if (lc == 0) {
#pragma unroll
                for (int j = 0; j < 4; ++j) {
                    int b = rg * 16 + lh * 4 + j;
                    unsigned qb = (fu(q_[j]) & ~3u) | tgp;
                    unsigned long long pk = ((unsigned long long)qb << 32) |
                                            (unsigned long long)fu(s_[j]);
                    __hip_atomic_store(&sg[(size_t)pt * 4096 + (size_t)b * 64 + cg * 2 + ct],
                                       pk, __ATOMIC_RELAXED, __HIP_MEMORY_SCOPE_AGENT);
                }
            }
#pragma unroll
            for (int j = 0; j < 4; ++j) {
                int b = rg * 16 + lh * 4 + j;
                unsigned zt = (fu(zz[j]) & ~3u) | tgp;
                __hip_atomic_store(&zg[(size_t)pt * 65536 + (size_t)b * 1024 + col],
                                   zt, __ATOMIC_RELAXED, __HIP_MEMORY_SCOPE_AGENT);
            }
        }
    }

    // ---- epilogue: stats for t=511 -> out[b, 511, col]
    {
        const unsigned tg = 0;   // (511+1) & 3
        const char* sladdr = (const char*)sg + (size_t)32768 /* parity 1 */ + srow_off;
        u32x4 q0, q1;
        asm volatile(
            "global_load_dwordx4 %0, %2, off sc0 sc1\n\t"
            "global_load_dwordx4 %1, %2, off offset:16 sc0 sc1\n\t"
            "s_waitcnt vmcnt(0)"
            : "=&v"(q0), "=&v"(q1) : "v"(sladdr) : "memory");
        while ((((q0.y ^ tg) | (q0.w ^ tg) | (q1.y ^ tg) | (q1.w ^ tg)) & 3u) != 0u) {
            asm volatile(
                "global_load_dwordx4 %0, %2, off sc0 sc1\n\t"
                "global_load_dwordx4 %1, %2, off offset:16 sc0 sc1\n\t"
                "s_waitcnt vmcnt(0)"
                : "=&v"(q0), "=&v"(q1) : "v"(sladdr) : "memory");
        }
        float S = uf(q0.x) + uf(q0.z) + uf(q1.x) + uf(q1.z);
        float Q = uf(q0.y) + uf(q0.w) + uf(q1.y) + uf(q1.w);
#pragma unroll
        for (int m = 1; m < 16; m <<= 1) {
            S += __shfl_xor(S, m);
            Q += __shfl_xor(Q, m);
        }
        float mu  = S * (1.0f / H_);
        float var = Q * (1.0f / H_) - mu * mu;
        if ((tid & 15) == 0) {
            smu[tid >> 4] = mu;
            srs[tid >> 4] = rsqrtf(var + LN_EPS);
        }
        __syncthreads();
        if (kh == 0) {
#pragma unroll
            for (int j = 0; j < 4; ++j) {
                int r = lh * 4 + j;
                int b = rg * 16 + r;
                float o = tf((zz[j] - smu[r]) * srs[r] * gmv + btv);
                out[((size_t)b * T_ + (T_ - 1)) * H_ + col] = o;
            }
        }
    }
}

// ---------------------------------------------------------------------------
extern "C" void kernel_launch(void* const* d_in, const int* in_sizes, int n_in,
                              void* d_out, int out_size, void* d_ws, size_t ws_size,
                              hipStream_t stream)
{
    const float* X     = (const float*)d_in[0];
    const float* W     = (const float*)d_in[1];
    const float* U     = (const float*)d_in[2];
    const float* bias  = (const float*)d_in[3];
    const float* gamma = (const float*)d_in[4];
    const float* beta  = (const float*)d_in[5];
    float* out = (float*)d_out;

    // ws: [z 2x256KB][stats 2x32KB]
    unsigned int* zg = (unsigned int*)d_ws;
    unsigned long long* sg = (unsigned long long*)((char*)d_ws + 524288);

    hipMemsetAsync(d_ws, 0, 524288 + 65536, stream);

    gemm1_kernel<<<dim3(512, 16), 256, 0, stream>>>(X, W, bias, out);

    const int lds_bytes = 32 * UPAD * 2 * 2 + 4096 + 4096 + 2048 + 64 + 64;
    hipFuncSetAttribute((const void*)rnn_kernel,
                        hipFuncAttributeMaxDynamicSharedMemorySize, lds_bytes);
    rnn_kernel<<<128, 256, lds_bytes, stream>>>(U, gamma, beta, out, zg, sg);
}